// Round 7
// baseline (129.222 us; speedup 1.0000x reference)
//
#include <hip/hip_runtime.h>
#include <hip/hip_bf16.h>
#include <math.h>

// HyperbolicMLR: out[b,c] = -asinh( 2*sc_diff_a / ((1+diff_norm2)*|a_c|) )
// R7: exact m201 phase skeleton: reads+stage BEFORE barrier, lgkmcnt(0) after
// barrier, MFMA cluster, end barrier (2 barriers/phase). vmcnt(4) gate at
// q2/q4 wave-local before end barrier. Geometry/swizzle identical to R6.

#define EPSF 1e-15f
#define MAXN 0.99999f   // (1 - 1e-5) / sqrt(c), c = 1

constexpr int Bdim = 4096;
constexpr int Ddim = 1024;
constexpr int Cdim = 4096;

typedef __bf16 bf16x8 __attribute__((ext_vector_type(8)));
typedef float  f32x4  __attribute__((ext_vector_type(4)));
typedef unsigned short u16;

__device__ __forceinline__ u16 f2bf(float f) {
  __hip_bfloat16 h = __float2bfloat16(f);   // RNE
  return *reinterpret_cast<const u16*>(&h);
}

__device__ __forceinline__ void gl_lds16(const u16* g, u16* l) {
  __builtin_amdgcn_global_load_lds(
      (const __attribute__((address_space(1))) void*)g,
      (__attribute__((address_space(3))) void*)l, 16, 0, 0);
}

// ---------------- prep kernels (unchanged, proven) ----------------

__global__ __launch_bounds__(256) void prep_x(const float* __restrict__ x,
                                              u16* __restrict__ xb,
                                              float* __restrict__ x2o) {
  const int b = blockIdx.x, t = threadIdx.x;
  float4 v = ((const float4*)(x + (size_t)b * Ddim))[t];
  float s = v.x * v.x + v.y * v.y + v.z * v.z + v.w * v.w;
  __shared__ float red[4];
#pragma unroll
  for (int o = 32; o > 0; o >>= 1) s += __shfl_down(s, o);
  if ((t & 63) == 0) red[t >> 6] = s;
  __syncthreads();
  s = red[0] + red[1] + red[2] + red[3];
  float norm  = sqrtf(s);
  float xn    = fmaxf(norm, EPSF);
  float scale = (xn > MAXN) ? (MAXN / xn) : 1.0f;
  if (t == 0) x2o[b] = s * scale * scale;
  ushort4 o4;
  o4.x = f2bf(v.x * scale); o4.y = f2bf(v.y * scale);
  o4.z = f2bf(v.z * scale); o4.w = f2bf(v.w * scale);
  ((ushort4*)(xb + (size_t)b * Ddim))[t] = o4;
}

// P row c -> PA row ((c>>4)<<5)+(c&15); A row c -> +16 (16-row interleave).
__global__ __launch_bounds__(256) void prep_pa(const float* __restrict__ a,
                                               const float* __restrict__ p,
                                               u16* __restrict__ pab,
                                               float* __restrict__ p2o,
                                               float* __restrict__ pao,
                                               float* __restrict__ ano) {
  const int c = blockIdx.x, t = threadIdx.x;
  float4 av = ((const float4*)(a + (size_t)c * Ddim))[t];
  float4 pv = ((const float4*)(p + (size_t)c * Ddim))[t];
  float sp2 = pv.x * pv.x + pv.y * pv.y + pv.z * pv.z + pv.w * pv.w;
  float spa = pv.x * av.x + pv.y * av.y + pv.z * av.z + pv.w * av.w;
  float sa2 = av.x * av.x + av.y * av.y + av.z * av.z + av.w * av.w;
  __shared__ float red[12];
#pragma unroll
  for (int o = 32; o > 0; o >>= 1) {
    sp2 += __shfl_down(sp2, o);
    spa += __shfl_down(spa, o);
    sa2 += __shfl_down(sa2, o);
  }
  if ((t & 63) == 0) { int w = t >> 6; red[w] = sp2; red[4 + w] = spa; red[8 + w] = sa2; }
  __syncthreads();
  if (t == 0) {
    p2o[c] = red[0] + red[1] + red[2] + red[3];
    pao[c] = red[4] + red[5] + red[6] + red[7];
    ano[c] = sqrtf(red[8] + red[9] + red[10] + red[11]);
  }
  const int prP = ((c >> 4) << 5) + (c & 15);
  ushort4 oa, op;
  oa.x = f2bf(av.x); oa.y = f2bf(av.y); oa.z = f2bf(av.z); oa.w = f2bf(av.w);
  op.x = f2bf(pv.x); op.y = f2bf(pv.y); op.z = f2bf(pv.z); op.w = f2bf(pv.w);
  ((ushort4*)(pab + (size_t)prP * Ddim))[t]        = op;
  ((ushort4*)(pab + (size_t)(prP + 16) * Ddim))[t] = oa;
}

// ---------------- 8-phase fused GEMM + epilogue ----------------

#define BAR_LGKM() do {                                          \
    __builtin_amdgcn_s_barrier();                                \
    asm volatile("s_waitcnt lgkmcnt(0)" ::: "memory");           \
    __builtin_amdgcn_sched_barrier(0);                           \
  } while (0)

#define ENDBAR() do {                                            \
    __builtin_amdgcn_s_barrier();                                \
    __builtin_amdgcn_sched_barrier(0);                           \
  } while (0)

#define GATE4() asm volatile("s_waitcnt vmcnt(4)" ::: "memory")
#define GATE0() asm volatile("s_waitcnt vmcnt(0)" ::: "memory")

__global__ __launch_bounds__(512, 2) void gemm_ep(
    const u16* __restrict__ xb, const u16* __restrict__ pab,
    const float* __restrict__ x2g, const float* __restrict__ p2g,
    const float* __restrict__ pag, const float* __restrict__ ang,
    float* __restrict__ out) {
  // [buf][k-half][256 rows x 32 u16] ; 64-B rows (R5-proven swizzle geometry)
  __shared__ u16 Xs[2][2][8192];     // 64 KiB
  __shared__ u16 PAs[2][2][8192];    // 64 KiB

  const int t = threadIdx.x;         // 0..511

  // XCD-aware bijective swizzle: 512 blocks = 8 chunks x 64
  const int flat  = blockIdx.y * 32 + blockIdx.x;
  const int swz   = (flat & 7) * 64 + (flat >> 3);
  const int chunk = swz >> 6;                 // 0..7
  const int local = swz & 63;
  const int bx = chunk * 4 + (local & 3);     // 0..31  PA col-group
  const int by = local >> 2;                  // 0..15  X row-group

  const int lane = t & 63;
  const int wid  = t >> 6;       // 0..7
  const int wr   = wid >> 2;     // 0..1  (row half: 128 rows)
  const int wc   = wid & 3;      // 0..3  (PA quarter: 64 rows)

  // ---- staging mapping: thread t covers (r0 = t>>2, slot = t&3) of a
  // 128-row sub-unit; source k-chunk pre-swizzled (XOR involution).
  const int r0  = t >> 2;                              // 0..127
  const int sw8 = ((t & 3) ^ ((r0 >> 1) & 3)) * 8;     // u16
  const u16* xsrc  = xb  + (size_t)(by * 256 + r0) * Ddim + sw8;
  const u16* pasrc = pab + (size_t)(bx * 256 + r0) * Ddim + sw8;
  const int t8 = t * 8;
  const size_t half = (size_t)128 * Ddim;

  // ---- fragment read offsets (per sub-tile, u16 units)
  const int arow = wr * 128 + (lane & 15);
  const int brow = wc * 64  + (lane & 15);
  const int aoff = arow * 32 + (((lane >> 4) ^ ((arow >> 1) & 3)) * 8);
  const int boff = brow * 32 + (((lane >> 4) ^ ((brow >> 1) & 3)) * 8);

  f32x4 acc[8][4];
  const f32x4 zero = {0.f, 0.f, 0.f, 0.f};
#pragma unroll
  for (int m = 0; m < 8; ++m)
#pragma unroll
    for (int n = 0; n < 4; ++n) acc[m][n] = zero;

  bf16x8 bv[4];
  bf16x8 av0, av1, av2, av3;

#define LOADBV(PR, XB) do {                                      \
    _Pragma("unroll")                                            \
    for (int nf = 0; nf < 4; ++nf)                               \
      bv[nf] = *(const bf16x8*)&(PR)[(XB) + boff + nf * 512];    \
  } while (0)

#define LOADA(XR, XB) do {                                       \
    av0 = *(const bf16x8*)&(XR)[(XB) + aoff];                    \
    av1 = *(const bf16x8*)&(XR)[(XB) + aoff + 512];              \
    av2 = *(const bf16x8*)&(XR)[(XB) + aoff + 1024];             \
    av3 = *(const bf16x8*)&(XR)[(XB) + aoff + 1536];             \
  } while (0)

#define MFMA16(ABASE) do {                                       \
    __builtin_amdgcn_s_setprio(1);                               \
    _Pragma("unroll")                                            \
    for (int nf = 0; nf < 4; ++nf) {                             \
      acc[(ABASE)+0][nf] = __builtin_amdgcn_mfma_f32_16x16x32_bf16(av0, bv[nf], acc[(ABASE)+0][nf], 0, 0, 0); \
      acc[(ABASE)+1][nf] = __builtin_amdgcn_mfma_f32_16x16x32_bf16(av1, bv[nf], acc[(ABASE)+1][nf], 0, 0, 0); \
      acc[(ABASE)+2][nf] = __builtin_amdgcn_mfma_f32_16x16x32_bf16(av2, bv[nf], acc[(ABASE)+2][nf], 0, 0, 0); \
      acc[(ABASE)+3][nf] = __builtin_amdgcn_mfma_f32_16x16x32_bf16(av3, bv[nf], acc[(ABASE)+3][nf], 0, 0, 0); \
    }                                                            \
    __builtin_amdgcn_s_setprio(0);                               \
  } while (0)

  // running source pointers for the NEXT tile (tile 1 first)
  const u16* xgp = xsrc  + 64;
  const u16* pgp = pasrc + 64;

  // ---- prologue: stage tile 0 fully, FIFO {X.k0, PA.k0, X.k1, PA.k1}
  {
    u16* Xw  = (u16*)&Xs[0][0][0];
    u16* PAw = (u16*)&PAs[0][0][0];
    gl_lds16(xsrc,             Xw + t8);
    gl_lds16(xsrc + half,      Xw + 4096 + t8);
    gl_lds16(pasrc,            PAw + t8);
    gl_lds16(pasrc + half,     PAw + 4096 + t8);
    gl_lds16(xsrc + 32,        Xw + 8192 + t8);
    gl_lds16(xsrc + half + 32, Xw + 8192 + 4096 + t8);
    gl_lds16(pasrc + 32,       PAw + 8192 + t8);
    gl_lds16(pasrc + half + 32,PAw + 8192 + 4096 + t8);
  }
  GATE4();                       // k0 units retired (4 still in flight)
  __builtin_amdgcn_s_barrier();
  __builtin_amdgcn_sched_barrier(0);

  // ---- main loop: tiles 0..14, staging tile T+1 (1 half-unit per phase)
  // Phase = [reads + stage] -> barrier -> lgkm(0) -> MFMA -> [gate] -> barrier
  for (int T = 0; T < 15; ++T) {
    const int b = T & 1;
    const u16* Xr  = &Xs[b][0][0];
    const u16* PAr = &PAs[b][0][0];
    u16* Xw  = (u16*)&Xs[b ^ 1][0][0];
    u16* PAw = (u16*)&PAs[b ^ 1][0][0];

    // q1: k0, m-half A | stage X.k0(T+1)
    LOADBV(PAr, 0);
    LOADA(Xr, 0);
    gl_lds16(xgp,        Xw + t8);
    gl_lds16(xgp + half, Xw + 4096 + t8);
    BAR_LGKM();
    MFMA16(0);
    ENDBAR();

    // q2: k0, m-half B | stage PA.k0(T+1) | gate: k1(T) retires
    LOADA(Xr, 2048);
    gl_lds16(pgp,        PAw + t8);
    gl_lds16(pgp + half, PAw + 4096 + t8);
    BAR_LGKM();
    MFMA16(4);
    GATE4();
    ENDBAR();

    // q3: k1, m-half A | stage X.k1(T+1)
    LOADBV(PAr, 8192);
    LOADA(Xr, 8192);
    gl_lds16(xgp + 32,        Xw + 8192 + t8);
    gl_lds16(xgp + half + 32, Xw + 8192 + 4096 + t8);
    BAR_LGKM();
    MFMA16(0);
    ENDBAR();

    // q4: k1, m-half B | stage PA.k1(T+1) | gate: k0(T+1) retires
    LOADA(Xr, 8192 + 2048);
    gl_lds16(pgp + 32,        PAw + 8192 + t8);
    gl_lds16(pgp + half + 32, PAw + 8192 + 4096 + t8);
    BAR_LGKM();
    MFMA16(4);
    xgp += 64; pgp += 64;
    GATE4();
    ENDBAR();
  }

  // ---- tile 15 (buf 1), no staging
  {
    const u16* Xr  = &Xs[1][0][0];
    const u16* PAr = &PAs[1][0][0];
    LOADBV(PAr, 0);
    LOADA(Xr, 0);
    BAR_LGKM();
    MFMA16(0);
    ENDBAR();

    LOADA(Xr, 2048);
    BAR_LGKM();
    MFMA16(4);
    GATE0();                     // k1(15) fully staged
    ENDBAR();

    LOADBV(PAr, 8192);
    LOADA(Xr, 8192);
    BAR_LGKM();
    MFMA16(0);
    ENDBAR();

    LOADA(Xr, 8192 + 2048);
    BAR_LGKM();
    MFMA16(4);
  }

#undef LOADBV
#undef LOADA
#undef MFMA16

  // ---- epilogue: C/D layout col = lane&15, row = (lane>>4)*4 + j.
  // n even -> px, n odd -> xa, same 16 output cols per (even,odd) pair.
#pragma unroll
  for (int m = 0; m < 8; ++m) {
    const int rl0 = by * 256 + wr * 128 + m * 16 + (lane >> 4) * 4;
    float x2r[4];
#pragma unroll
    for (int j = 0; j < 4; ++j) x2r[j] = x2g[rl0 + j];
#pragma unroll
    for (int g = 0; g < 2; ++g) {
      const int cl = (bx * 8 + wc * 2 + g) * 16 + (lane & 15);
      const float p2c = p2g[cl];
      const float pac = pag[cl];
      const float anc = ang[cl];
      const float Bcc = 1.0f - p2c;
      f32x4 px4 = acc[m][2 * g];
      f32x4 xa4 = acc[m][2 * g + 1];
#pragma unroll
      for (int j = 0; j < 4; ++j) {
        const float px = px4[j];
        const float xa = xa4[j];
        const float Av  = 1.0f - 2.0f * px + x2r[j];
        const float den = fmaxf(1.0f - 2.0f * px + x2r[j] * p2c, EPSF);
        const float dn2 = fmaxf((Av * Av * p2c + Bcc * Bcc * x2r[j] - 2.0f * Av * Bcc * px) / (den * den), EPSF);
        const float sc  = (Bcc * xa - Av * pac) / den;
        const float dv  = fmaxf((1.0f + dn2) * anc, EPSF);
        const float z   = (2.0f * sc) / dv;
        // asinh: |z| <= ~0.13 on this data -> odd poly (err < 1e-6); exact fallback.
        const float z2 = z * z;
        float r;
        if (z2 > 0.04f) r = asinhf(z);
        else            r = z * (1.0f - z2 * (1.0f / 6.0f) + z2 * z2 * 0.075f);
        out[(size_t)rl0 * Cdim + j * Cdim + cl] = -r;
      }
    }
  }
}

extern "C" void kernel_launch(void* const* d_in, const int* in_sizes, int n_in,
                              void* d_out, int out_size, void* d_ws, size_t ws_size,
                              hipStream_t stream) {
  const float* x = (const float*)d_in[0];
  const float* a = (const float*)d_in[1];
  const float* p = (const float*)d_in[2];
  float* out = (float*)d_out;

  char* ws = (char*)d_ws;
  u16* xb  = (u16*)(ws);                                  // 8 MiB
  u16* pab = (u16*)(ws + (size_t)8 * 1024 * 1024);        // 16 MiB
  float* x2 = (float*)(ws + (size_t)24 * 1024 * 1024);    // stats
  float* p2 = x2 + Bdim;
  float* pa = p2 + Cdim;
  float* an = pa + Cdim;

  prep_x <<<Bdim, 256, 0, stream>>>(x, xb, x2);
  prep_pa<<<Cdim, 256, 0, stream>>>(a, p, pab, p2, pa, an);
  gemm_ep<<<dim3(32, 16), 512, 0, stream>>>(xb, pab, x2, p2, pa, an, out);
}

// Round 8
// 126.266 us; speedup vs baseline: 1.0234x; 1.0234x over previous
//
#include <hip/hip_runtime.h>
#include <hip/hip_bf16.h>
#include <math.h>

// HyperbolicMLR: out[b,c] = -asinh( 2*sc_diff_a / ((1+diff_norm2)*|a_c|) )
// R8: 256x256 tile as 32 BK=32 K-tiles with a 4-buffer LDS ring, prefetch
// distance 3 tiles -> every vmcnt gate has >=4 phases of lead (covers HBM
// latency). One gate (vmcnt(8)) per tile. Swizzle/epilogue same as R7.

#define EPSF 1e-15f
#define MAXN 0.99999f   // (1 - 1e-5) / sqrt(c), c = 1

constexpr int Bdim = 4096;
constexpr int Ddim = 1024;
constexpr int Cdim = 4096;

typedef __bf16 bf16x8 __attribute__((ext_vector_type(8)));
typedef float  f32x4  __attribute__((ext_vector_type(4)));
typedef unsigned short u16;

__device__ __forceinline__ u16 f2bf(float f) {
  __hip_bfloat16 h = __float2bfloat16(f);   // RNE
  return *reinterpret_cast<const u16*>(&h);
}

__device__ __forceinline__ void gl_lds16(const u16* g, u16* l) {
  __builtin_amdgcn_global_load_lds(
      (const __attribute__((address_space(1))) void*)g,
      (__attribute__((address_space(3))) void*)l, 16, 0, 0);
}

// ---------------- prep kernels (unchanged, proven) ----------------

__global__ __launch_bounds__(256) void prep_x(const float* __restrict__ x,
                                              u16* __restrict__ xb,
                                              float* __restrict__ x2o) {
  const int b = blockIdx.x, t = threadIdx.x;
  float4 v = ((const float4*)(x + (size_t)b * Ddim))[t];
  float s = v.x * v.x + v.y * v.y + v.z * v.z + v.w * v.w;
  __shared__ float red[4];
#pragma unroll
  for (int o = 32; o > 0; o >>= 1) s += __shfl_down(s, o);
  if ((t & 63) == 0) red[t >> 6] = s;
  __syncthreads();
  s = red[0] + red[1] + red[2] + red[3];
  float norm  = sqrtf(s);
  float xn    = fmaxf(norm, EPSF);
  float scale = (xn > MAXN) ? (MAXN / xn) : 1.0f;
  if (t == 0) x2o[b] = s * scale * scale;
  ushort4 o4;
  o4.x = f2bf(v.x * scale); o4.y = f2bf(v.y * scale);
  o4.z = f2bf(v.z * scale); o4.w = f2bf(v.w * scale);
  ((ushort4*)(xb + (size_t)b * Ddim))[t] = o4;
}

// P row c -> PA row ((c>>4)<<5)+(c&15); A row c -> +16 (16-row interleave).
__global__ __launch_bounds__(256) void prep_pa(const float* __restrict__ a,
                                               const float* __restrict__ p,
                                               u16* __restrict__ pab,
                                               float* __restrict__ p2o,
                                               float* __restrict__ pao,
                                               float* __restrict__ ano) {
  const int c = blockIdx.x, t = threadIdx.x;
  float4 av = ((const float4*)(a + (size_t)c * Ddim))[t];
  float4 pv = ((const float4*)(p + (size_t)c * Ddim))[t];
  float sp2 = pv.x * pv.x + pv.y * pv.y + pv.z * pv.z + pv.w * pv.w;
  float spa = pv.x * av.x + pv.y * av.y + pv.z * av.z + pv.w * av.w;
  float sa2 = av.x * av.x + av.y * av.y + av.z * av.z + av.w * av.w;
  __shared__ float red[12];
#pragma unroll
  for (int o = 32; o > 0; o >>= 1) {
    sp2 += __shfl_down(sp2, o);
    spa += __shfl_down(spa, o);
    sa2 += __shfl_down(sa2, o);
  }
  if ((t & 63) == 0) { int w = t >> 6; red[w] = sp2; red[4 + w] = spa; red[8 + w] = sa2; }
  __syncthreads();
  if (t == 0) {
    p2o[c] = red[0] + red[1] + red[2] + red[3];
    pao[c] = red[4] + red[5] + red[6] + red[7];
    ano[c] = sqrtf(red[8] + red[9] + red[10] + red[11]);
  }
  const int prP = ((c >> 4) << 5) + (c & 15);
  ushort4 oa, op;
  oa.x = f2bf(av.x); oa.y = f2bf(av.y); oa.z = f2bf(av.z); oa.w = f2bf(av.w);
  op.x = f2bf(pv.x); op.y = f2bf(pv.y); op.z = f2bf(pv.z); op.w = f2bf(pv.w);
  ((ushort4*)(pab + (size_t)prP * Ddim))[t]        = op;
  ((ushort4*)(pab + (size_t)(prP + 16) * Ddim))[t] = oa;
}

// ---------------- deep-pipelined fused GEMM + epilogue ----------------

#define BAR_LGKM() do {                                          \
    __builtin_amdgcn_s_barrier();                                \
    asm volatile("s_waitcnt lgkmcnt(0)" ::: "memory");           \
    __builtin_amdgcn_sched_barrier(0);                           \
  } while (0)

#define ENDBAR() do {                                            \
    __builtin_amdgcn_s_barrier();                                \
    __builtin_amdgcn_sched_barrier(0);                           \
  } while (0)

#define GATE8() asm volatile("s_waitcnt vmcnt(8)" ::: "memory")
#define GATE4() asm volatile("s_waitcnt vmcnt(4)" ::: "memory")
#define GATE0() asm volatile("s_waitcnt vmcnt(0)" ::: "memory")

__global__ __launch_bounds__(512, 2) void gemm_ep(
    const u16* __restrict__ xb, const u16* __restrict__ pab,
    const float* __restrict__ x2g, const float* __restrict__ p2g,
    const float* __restrict__ pag, const float* __restrict__ ang,
    float* __restrict__ out) {
  // 4-buffer ring, each buf = one BK=32 K-tile: 256 rows x 32 u16 (64-B rows)
  __shared__ u16 Xs[4][8192];      // 64 KiB
  __shared__ u16 PAs[4][8192];     // 64 KiB

  const int t = threadIdx.x;       // 0..511

  // XCD-aware bijective swizzle: 512 blocks = 8 chunks x 64
  const int flat  = blockIdx.y * 32 + blockIdx.x;
  const int swz   = (flat & 7) * 64 + (flat >> 3);
  const int chunk = swz >> 6;
  const int local = swz & 63;
  const int bx = chunk * 4 + (local & 3);     // 0..31  PA col-group
  const int by = local >> 2;                  // 0..15  X row-group

  const int lane = t & 63;
  const int wid  = t >> 6;       // 0..7
  const int wr   = wid >> 2;     // 0..1  (row half: 128 rows)
  const int wc   = wid & 3;      // 0..3  (PA quarter: 64 rows)

  // staging: thread t covers (r0 = t>>2, slot = t&3); source k-chunk
  // pre-swizzled (XOR involution, rule 21 both-sides).
  const int r0  = t >> 2;                              // 0..127
  const int sw8 = ((t & 3) ^ ((r0 >> 1) & 3)) * 8;     // u16
  const u16* xsrc  = xb  + (size_t)(by * 256 + r0) * Ddim + sw8;
  const u16* pasrc = pab + (size_t)(bx * 256 + r0) * Ddim + sw8;
  const int t8 = t * 8;
  const size_t half = (size_t)128 * Ddim;

  // fragment read offsets (per-tile buffer, u16 units)
  const int arow = wr * 128 + (lane & 15);
  const int brow = wc * 64  + (lane & 15);
  const int aoff = arow * 32 + (((lane >> 4) ^ ((arow >> 1) & 3)) * 8);
  const int boff = brow * 32 + (((lane >> 4) ^ ((brow >> 1) & 3)) * 8);

  f32x4 acc[8][4];
  const f32x4 zero = {0.f, 0.f, 0.f, 0.f};
#pragma unroll
  for (int m = 0; m < 8; ++m)
#pragma unroll
    for (int n = 0; n < 4; ++n) acc[m][n] = zero;

  bf16x8 bv[4];
  bf16x8 av0, av1, av2, av3;

#define LOADBV(PR) do {                                          \
    _Pragma("unroll")                                            \
    for (int nf = 0; nf < 4; ++nf)                               \
      bv[nf] = *(const bf16x8*)&(PR)[boff + nf * 512];           \
  } while (0)

#define LOADA(XR, XB) do {                                       \
    av0 = *(const bf16x8*)&(XR)[(XB) + aoff];                    \
    av1 = *(const bf16x8*)&(XR)[(XB) + aoff + 512];              \
    av2 = *(const bf16x8*)&(XR)[(XB) + aoff + 1024];             \
    av3 = *(const bf16x8*)&(XR)[(XB) + aoff + 1536];             \
  } while (0)

#define MFMA16(ABASE) do {                                       \
    __builtin_amdgcn_s_setprio(1);                               \
    _Pragma("unroll")                                            \
    for (int nf = 0; nf < 4; ++nf) {                             \
      acc[(ABASE)+0][nf] = __builtin_amdgcn_mfma_f32_16x16x32_bf16(av0, bv[nf], acc[(ABASE)+0][nf], 0, 0, 0); \
      acc[(ABASE)+1][nf] = __builtin_amdgcn_mfma_f32_16x16x32_bf16(av1, bv[nf], acc[(ABASE)+1][nf], 0, 0, 0); \
      acc[(ABASE)+2][nf] = __builtin_amdgcn_mfma_f32_16x16x32_bf16(av2, bv[nf], acc[(ABASE)+2][nf], 0, 0, 0); \
      acc[(ABASE)+3][nf] = __builtin_amdgcn_mfma_f32_16x16x32_bf16(av3, bv[nf], acc[(ABASE)+3][nf], 0, 0, 0); \
    }                                                            \
    __builtin_amdgcn_s_setprio(0);                               \
  } while (0)

  // TILE: phase A {bv+avA reads | stage X(T+3)} barrier lgkm MFMA(0..3) barrier
  //       phase B {avB reads    | stage PA(T+3)} barrier lgkm MFMA(4..7) GATE barrier
#define TILE(BI, DOSTAGE, GATE)  do {                            \
    const u16* Xr  = &Xs[(BI)][0];                               \
    const u16* PAr = &PAs[(BI)][0];                              \
    u16* Xw  = (u16*)&Xs[((BI)+3)&3][0];                         \
    u16* PAw = (u16*)&PAs[((BI)+3)&3][0];                        \
    LOADBV(PAr);                                                 \
    LOADA(Xr, 0);                                                \
    if (DOSTAGE) {                                               \
      gl_lds16(xgp,        Xw + t8);                             \
      gl_lds16(xgp + half, Xw + 4096 + t8);                      \
    }                                                            \
    BAR_LGKM();                                                  \
    MFMA16(0);                                                   \
    ENDBAR();                                                    \
    LOADA(Xr, 2048);                                             \
    if (DOSTAGE) {                                               \
      gl_lds16(pgp,        PAw + t8);                            \
      gl_lds16(pgp + half, PAw + 4096 + t8);                     \
      xgp += 32; pgp += 32;                                      \
    }                                                            \
    BAR_LGKM();                                                  \
    MFMA16(4);                                                   \
    GATE;                                                        \
    ENDBAR();                                                    \
  } while (0)

  // ---- prologue: stage tiles 0,1,2 (FIFO: X0,PA0,X1,PA1,X2,PA2 = 12 loads)
  {
#pragma unroll
    for (int T = 0; T < 3; ++T) {
      u16* Xw  = (u16*)&Xs[T][0];
      u16* PAw = (u16*)&PAs[T][0];
      gl_lds16(xsrc  + T * 32,        Xw + t8);
      gl_lds16(xsrc  + T * 32 + half, Xw + 4096 + t8);
      gl_lds16(pasrc + T * 32,        PAw + t8);
      gl_lds16(pasrc + T * 32 + half, PAw + 4096 + t8);
    }
  }
  const u16* xgp = xsrc  + 96;   // next staged tile = 3
  const u16* pgp = pasrc + 96;
  GATE8();                       // tile0's 4 loads retired
  __builtin_amdgcn_s_barrier();
  __builtin_amdgcn_sched_barrier(0);

  // ---- main: tiles 0..27 stage tiles 3..30, gate vmcnt(8) per tile
  for (int tt = 0; tt < 7; ++tt) {
    TILE(0, 1, GATE8());
    TILE(1, 1, GATE8());
    TILE(2, 1, GATE8());
    TILE(3, 1, GATE8());
  }
  // ---- tail: T=28 stages tile 31; T=29/30/31 drain
  TILE(0, 1, GATE8());
  TILE(1, 0, GATE4());
  TILE(2, 0, GATE0());
  TILE(3, 0, (void)0);

#undef TILE
#undef LOADBV
#undef LOADA
#undef MFMA16

  // ---- epilogue: C/D layout col = lane&15, row = (lane>>4)*4 + j.
  // n even -> px, n odd -> xa, same 16 output cols per (even,odd) pair.
#pragma unroll
  for (int m = 0; m < 8; ++m) {
    const int rl0 = by * 256 + wr * 128 + m * 16 + (lane >> 4) * 4;
    float x2r[4];
#pragma unroll
    for (int j = 0; j < 4; ++j) x2r[j] = x2g[rl0 + j];
#pragma unroll
    for (int g = 0; g < 2; ++g) {
      const int cl = (bx * 8 + wc * 2 + g) * 16 + (lane & 15);
      const float p2c = p2g[cl];
      const float pac = pag[cl];
      const float anc = ang[cl];
      const float Bcc = 1.0f - p2c;
      f32x4 px4 = acc[m][2 * g];
      f32x4 xa4 = acc[m][2 * g + 1];
#pragma unroll
      for (int j = 0; j < 4; ++j) {
        const float px = px4[j];
        const float xa = xa4[j];
        const float Av  = 1.0f - 2.0f * px + x2r[j];
        const float den = fmaxf(1.0f - 2.0f * px + x2r[j] * p2c, EPSF);
        const float dn2 = fmaxf((Av * Av * p2c + Bcc * Bcc * x2r[j] - 2.0f * Av * Bcc * px) / (den * den), EPSF);
        const float sc  = (Bcc * xa - Av * pac) / den;
        const float dv  = fmaxf((1.0f + dn2) * anc, EPSF);
        const float z   = (2.0f * sc) / dv;
        // asinh: |z| <= ~0.13 on this data -> odd poly; exact fallback.
        const float z2 = z * z;
        float r;
        if (z2 > 0.04f) r = asinhf(z);
        else            r = z * (1.0f - z2 * (1.0f / 6.0f) + z2 * z2 * 0.075f);
        out[(size_t)rl0 * Cdim + j * Cdim + cl] = -r;
      }
    }
  }
}

extern "C" void kernel_launch(void* const* d_in, const int* in_sizes, int n_in,
                              void* d_out, int out_size, void* d_ws, size_t ws_size,
                              hipStream_t stream) {
  const float* x = (const float*)d_in[0];
  const float* a = (const float*)d_in[1];
  const float* p = (const float*)d_in[2];
  float* out = (float*)d_out;

  char* ws = (char*)d_ws;
  u16* xb  = (u16*)(ws);                                  // 8 MiB
  u16* pab = (u16*)(ws + (size_t)8 * 1024 * 1024);        // 16 MiB
  float* x2 = (float*)(ws + (size_t)24 * 1024 * 1024);    // stats
  float* p2 = x2 + Bdim;
  float* pa = p2 + Cdim;
  float* an = pa + Cdim;

  prep_x <<<Bdim, 256, 0, stream>>>(x, xb, x2);
  prep_pa<<<Cdim, 256, 0, stream>>>(a, p, pab, p2, pa, an);
  gemm_ep<<<dim3(32, 16), 512, 0, stream>>>(xb, pab, x2, p2, pa, an, out);
}

// Round 9
// 124.638 us; speedup vs baseline: 1.0368x; 1.0131x over previous
//
#include <hip/hip_runtime.h>
#include <hip/hip_bf16.h>
#include <math.h>

// HyperbolicMLR: out[b,c] = -asinh( 2*sc_diff_a / ((1+diff_norm2)*|a_c|) )
// R9: single barrier + single counted vmcnt gate per BK=32 tile (ring-4,
// lead-3), and instruction-level interleave inside the tile: second-half
// A-fragment ds_reads issue between MFMA groups into recycled registers,
// so the LDS drain hides under MFMA issue (AITER mechanism, plain HIP).

#define EPSF 1e-15f
#define MAXN 0.99999f   // (1 - 1e-5) / sqrt(c), c = 1

constexpr int Bdim = 4096;
constexpr int Ddim = 1024;
constexpr int Cdim = 4096;

typedef __bf16 bf16x8 __attribute__((ext_vector_type(8)));
typedef float  f32x4  __attribute__((ext_vector_type(4)));
typedef unsigned short u16;

__device__ __forceinline__ u16 f2bf(float f) {
  __hip_bfloat16 h = __float2bfloat16(f);   // RNE
  return *reinterpret_cast<const u16*>(&h);
}

__device__ __forceinline__ void gl_lds16(const u16* g, u16* l) {
  __builtin_amdgcn_global_load_lds(
      (const __attribute__((address_space(1))) void*)g,
      (__attribute__((address_space(3))) void*)l, 16, 0, 0);
}

// ---------------- prep kernels (unchanged, proven) ----------------

__global__ __launch_bounds__(256) void prep_x(const float* __restrict__ x,
                                              u16* __restrict__ xb,
                                              float* __restrict__ x2o) {
  const int b = blockIdx.x, t = threadIdx.x;
  float4 v = ((const float4*)(x + (size_t)b * Ddim))[t];
  float s = v.x * v.x + v.y * v.y + v.z * v.z + v.w * v.w;
  __shared__ float red[4];
#pragma unroll
  for (int o = 32; o > 0; o >>= 1) s += __shfl_down(s, o);
  if ((t & 63) == 0) red[t >> 6] = s;
  __syncthreads();
  s = red[0] + red[1] + red[2] + red[3];
  float norm  = sqrtf(s);
  float xn    = fmaxf(norm, EPSF);
  float scale = (xn > MAXN) ? (MAXN / xn) : 1.0f;
  if (t == 0) x2o[b] = s * scale * scale;
  ushort4 o4;
  o4.x = f2bf(v.x * scale); o4.y = f2bf(v.y * scale);
  o4.z = f2bf(v.z * scale); o4.w = f2bf(v.w * scale);
  ((ushort4*)(xb + (size_t)b * Ddim))[t] = o4;
}

// P row c -> PA row ((c>>4)<<5)+(c&15); A row c -> +16 (16-row interleave).
__global__ __launch_bounds__(256) void prep_pa(const float* __restrict__ a,
                                               const float* __restrict__ p,
                                               u16* __restrict__ pab,
                                               float* __restrict__ p2o,
                                               float* __restrict__ pao,
                                               float* __restrict__ ano) {
  const int c = blockIdx.x, t = threadIdx.x;
  float4 av = ((const float4*)(a + (size_t)c * Ddim))[t];
  float4 pv = ((const float4*)(p + (size_t)c * Ddim))[t];
  float sp2 = pv.x * pv.x + pv.y * pv.y + pv.z * pv.z + pv.w * pv.w;
  float spa = pv.x * av.x + pv.y * av.y + pv.z * av.z + pv.w * av.w;
  float sa2 = av.x * av.x + av.y * av.y + av.z * av.z + av.w * av.w;
  __shared__ float red[12];
#pragma unroll
  for (int o = 32; o > 0; o >>= 1) {
    sp2 += __shfl_down(sp2, o);
    spa += __shfl_down(spa, o);
    sa2 += __shfl_down(sa2, o);
  }
  if ((t & 63) == 0) { int w = t >> 6; red[w] = sp2; red[4 + w] = spa; red[8 + w] = sa2; }
  __syncthreads();
  if (t == 0) {
    p2o[c] = red[0] + red[1] + red[2] + red[3];
    pao[c] = red[4] + red[5] + red[6] + red[7];
    ano[c] = sqrtf(red[8] + red[9] + red[10] + red[11]);
  }
  const int prP = ((c >> 4) << 5) + (c & 15);
  ushort4 oa, op;
  oa.x = f2bf(av.x); oa.y = f2bf(av.y); oa.z = f2bf(av.z); oa.w = f2bf(av.w);
  op.x = f2bf(pv.x); op.y = f2bf(pv.y); op.z = f2bf(pv.z); op.w = f2bf(pv.w);
  ((ushort4*)(pab + (size_t)prP * Ddim))[t]        = op;
  ((ushort4*)(pab + (size_t)(prP + 16) * Ddim))[t] = oa;
}

// ---------------- fused GEMM + epilogue ----------------

#define SBAR0() __builtin_amdgcn_sched_barrier(0)
#define GATE8() asm volatile("s_waitcnt vmcnt(8)" ::: "memory")
#define GATE4() asm volatile("s_waitcnt vmcnt(4)" ::: "memory")
#define GATE0() asm volatile("s_waitcnt vmcnt(0)" ::: "memory")

__global__ __launch_bounds__(512, 2) void gemm_ep(
    const u16* __restrict__ xb, const u16* __restrict__ pab,
    const float* __restrict__ x2g, const float* __restrict__ p2g,
    const float* __restrict__ pag, const float* __restrict__ ang,
    float* __restrict__ out) {
  // ring of 4 BK=32 K-tiles: 256 rows x 32 u16 (64-B rows), X and PA
  __shared__ u16 Xs[4][8192];      // 64 KiB
  __shared__ u16 PAs[4][8192];     // 64 KiB

  const int t = threadIdx.x;       // 0..511

  // XCD-aware bijective swizzle: 512 blocks = 8 chunks x 64
  const int flat  = blockIdx.y * 32 + blockIdx.x;
  const int swz   = (flat & 7) * 64 + (flat >> 3);
  const int chunk = swz >> 6;
  const int local = swz & 63;
  const int bx = chunk * 4 + (local & 3);     // 0..31  PA col-group
  const int by = local >> 2;                  // 0..15  X row-group

  const int lane = t & 63;
  const int wid  = t >> 6;       // 0..7
  const int wr   = wid >> 2;     // 0..1  (row half: 128 rows)
  const int wc   = wid & 3;      // 0..3  (PA quarter: 64 rows)

  // staging: thread t covers (r0 = t>>2, slot = t&3); source k-chunk
  // pre-swizzled (XOR involution, rule 21 both-sides).
  const int r0  = t >> 2;                              // 0..127
  const int sw8 = ((t & 3) ^ ((r0 >> 1) & 3)) * 8;     // u16
  const u16* xsrc  = xb  + (size_t)(by * 256 + r0) * Ddim + sw8;
  const u16* pasrc = pab + (size_t)(bx * 256 + r0) * Ddim + sw8;
  const int t8 = t * 8;
  const size_t half = (size_t)128 * Ddim;

  // fragment read offsets (per-tile buffer, u16 units)
  const int arow = wr * 128 + (lane & 15);
  const int brow = wc * 64  + (lane & 15);
  const int aoff = arow * 32 + (((lane >> 4) ^ ((arow >> 1) & 3)) * 8);
  const int boff = brow * 32 + (((lane >> 4) ^ ((brow >> 1) & 3)) * 8);

  f32x4 acc[8][4];
  const f32x4 zero = {0.f, 0.f, 0.f, 0.f};
#pragma unroll
  for (int m = 0; m < 8; ++m)
#pragma unroll
    for (int n = 0; n < 4; ++n) acc[m][n] = zero;

#define MROW(M, AV) do {                                                     \
    acc[M][0] = __builtin_amdgcn_mfma_f32_16x16x32_bf16(AV, bv0, acc[M][0], 0, 0, 0); \
    acc[M][1] = __builtin_amdgcn_mfma_f32_16x16x32_bf16(AV, bv1, acc[M][1], 0, 0, 0); \
    acc[M][2] = __builtin_amdgcn_mfma_f32_16x16x32_bf16(AV, bv2, acc[M][2], 0, 0, 0); \
    acc[M][3] = __builtin_amdgcn_mfma_f32_16x16x32_bf16(AV, bv3, acc[M][3], 0, 0, 0); \
  } while (0)

  // One barrier + one gate per tile; rolling-register read/MFMA interleave.
#define TILE(BI, DOSTAGE, GATE) do {                                  \
    GATE;                                                             \
    __builtin_amdgcn_s_barrier();                                     \
    SBAR0();                                                          \
    if (DOSTAGE) {                                                    \
      u16* Xw  = (u16*)&Xs[((BI)+3)&3][0];                            \
      u16* PAw = (u16*)&PAs[((BI)+3)&3][0];                           \
      gl_lds16(xgp,        Xw + t8);                                  \
      gl_lds16(xgp + half, Xw + 4096 + t8);                           \
      gl_lds16(pgp,        PAw + t8);                                 \
      gl_lds16(pgp + half, PAw + 4096 + t8);                          \
      xgp += 32; pgp += 32;                                           \
    }                                                                 \
    const u16* Xr  = &Xs[(BI)][0];                                    \
    const u16* PAr = &PAs[(BI)][0];                                   \
    bf16x8 bv0 = *(const bf16x8*)&PAr[boff];                          \
    bf16x8 bv1 = *(const bf16x8*)&PAr[boff + 512];                    \
    bf16x8 bv2 = *(const bf16x8*)&PAr[boff + 1024];                   \
    bf16x8 bv3 = *(const bf16x8*)&PAr[boff + 1536];                   \
    bf16x8 a0 = *(const bf16x8*)&Xr[aoff];                            \
    bf16x8 a1 = *(const bf16x8*)&Xr[aoff + 512];                      \
    bf16x8 a2 = *(const bf16x8*)&Xr[aoff + 1024];                     \
    bf16x8 a3 = *(const bf16x8*)&Xr[aoff + 1536];                     \
    asm volatile("s_waitcnt lgkmcnt(0)" ::: "memory");                \
    SBAR0();                                                          \
    __builtin_amdgcn_s_setprio(1);                                    \
    MROW(0, a0); MROW(1, a1);                                         \
    SBAR0();                                                          \
    a0 = *(const bf16x8*)&Xr[aoff + 2048];                            \
    a1 = *(const bf16x8*)&Xr[aoff + 2560];                            \
    SBAR0();                                                          \
    MROW(2, a2); MROW(3, a3);                                         \
    SBAR0();                                                          \
    a2 = *(const bf16x8*)&Xr[aoff + 3072];                            \
    a3 = *(const bf16x8*)&Xr[aoff + 3584];                            \
    SBAR0();                                                          \
    asm volatile("s_waitcnt lgkmcnt(2)" ::: "memory");                \
    SBAR0();                                                          \
    MROW(4, a0); MROW(5, a1);                                         \
    asm volatile("s_waitcnt lgkmcnt(0)" ::: "memory");                \
    SBAR0();                                                          \
    MROW(6, a2); MROW(7, a3);                                         \
    __builtin_amdgcn_s_setprio(0);                                    \
  } while (0)

  // ---- prologue: stage tiles 0,1,2 (12 loads, FIFO 4 per tile)
#pragma unroll
  for (int T = 0; T < 3; ++T) {
    u16* Xw  = (u16*)&Xs[T][0];
    u16* PAw = (u16*)&PAs[T][0];
    gl_lds16(xsrc  + T * 32,        Xw + t8);
    gl_lds16(xsrc  + T * 32 + half, Xw + 4096 + t8);
    gl_lds16(pasrc + T * 32,        PAw + t8);
    gl_lds16(pasrc + T * 32 + half, PAw + 4096 + t8);
  }
  const u16* xgp = xsrc  + 96;   // next staged tile = 3
  const u16* pgp = pasrc + 96;

  // ---- main: tiles 0..27 (stage 3..30), then 28 (stages 31), 29..31 drain
  for (int g = 0; g < 7; ++g) {
    TILE(0, 1, GATE8());
    TILE(1, 1, GATE8());
    TILE(2, 1, GATE8());
    TILE(3, 1, GATE8());
  }
  TILE(0, 1, GATE8());   // tile 28, stages tile 31
  TILE(1, 0, GATE8());   // tile 29: outstanding 12 -> retire tile 29's 4
  TILE(2, 0, GATE4());   // tile 30
  TILE(3, 0, GATE0());   // tile 31

#undef TILE
#undef MROW

  // ---- epilogue: C/D layout col = lane&15, row = (lane>>4)*4 + j.
  // n even -> px, n odd -> xa, same 16 output cols per (even,odd) pair.
#pragma unroll
  for (int m = 0; m < 8; ++m) {
    const int rl0 = by * 256 + wr * 128 + m * 16 + (lane >> 4) * 4;
    float x2r[4];
#pragma unroll
    for (int j = 0; j < 4; ++j) x2r[j] = x2g[rl0 + j];
#pragma unroll
    for (int g = 0; g < 2; ++g) {
      const int cl = (bx * 8 + wc * 2 + g) * 16 + (lane & 15);
      const float p2c = p2g[cl];
      const float pac = pag[cl];
      const float anc = ang[cl];
      const float Bcc = 1.0f - p2c;
      f32x4 px4 = acc[m][2 * g];
      f32x4 xa4 = acc[m][2 * g + 1];
#pragma unroll
      for (int j = 0; j < 4; ++j) {
        const float px = px4[j];
        const float xa = xa4[j];
        const float Av  = 1.0f - 2.0f * px + x2r[j];
        const float den = fmaxf(1.0f - 2.0f * px + x2r[j] * p2c, EPSF);
        const float dn2 = fmaxf((Av * Av * p2c + Bcc * Bcc * x2r[j] - 2.0f * Av * Bcc * px) / (den * den), EPSF);
        const float sc  = (Bcc * xa - Av * pac) / den;
        const float dv  = fmaxf((1.0f + dn2) * anc, EPSF);
        const float z   = (2.0f * sc) / dv;
        // asinh: |z| <= ~0.13 on this data -> odd poly; exact fallback.
        const float z2 = z * z;
        float r;
        if (z2 > 0.04f) r = asinhf(z);
        else            r = z * (1.0f - z2 * (1.0f / 6.0f) + z2 * z2 * 0.075f);
        out[(size_t)rl0 * Cdim + j * Cdim + cl] = -r;
      }
    }
  }
}

extern "C" void kernel_launch(void* const* d_in, const int* in_sizes, int n_in,
                              void* d_out, int out_size, void* d_ws, size_t ws_size,
                              hipStream_t stream) {
  const float* x = (const float*)d_in[0];
  const float* a = (const float*)d_in[1];
  const float* p = (const float*)d_in[2];
  float* out = (float*)d_out;

  char* ws = (char*)d_ws;
  u16* xb  = (u16*)(ws);                                  // 8 MiB
  u16* pab = (u16*)(ws + (size_t)8 * 1024 * 1024);        // 16 MiB
  float* x2 = (float*)(ws + (size_t)24 * 1024 * 1024);    // stats
  float* p2 = x2 + Bdim;
  float* pa = p2 + Cdim;
  float* an = pa + Cdim;

  prep_x <<<Bdim, 256, 0, stream>>>(x, xb, x2);
  prep_pa<<<Cdim, 256, 0, stream>>>(a, p, pab, p2, pa, an);
  gemm_ep<<<dim3(32, 16), 512, 0, stream>>>(xb, pab, x2, p2, pa, an, out);
}